// Round 13
// baseline (779.545 us; speedup 1.0000x reference)
//
#include <hip/hip_runtime.h>
#include <hip/hip_bf16.h>

// Problem constants (fixed by the reference)
#define B_DIM   16384
#define IN_DIM  512
#define H_DIM   512
#define K_DIM   1024          // IN + H concatenated
#define N4H     2048          // 4*H
#define BH      (B_DIM * H_DIM)

typedef __attribute__((ext_vector_type(8))) short  short8;   // 8 bf16 = one MFMA operand
typedef __attribute__((ext_vector_type(4))) short  short4v;  // 4 bf16 = 8B write
typedef __attribute__((ext_vector_type(4))) float  f32x4;    // MFMA accumulator

__device__ inline void async_load16(const void* g, void* l) {
    __builtin_amdgcn_global_load_lds(
        (const __attribute__((address_space(1))) void*)g,
        (__attribute__((address_space(3)))       void*)l, 16, 0, 0);
}

__device__ inline short bf16bits(float f) {
    __hip_bfloat16 b = __float2bfloat16(f);
    return *reinterpret_cast<short*>(&b);
}

__device__ inline float sigmoidf_(float v) {
    return 1.0f / (1.0f + __expf(-v));
}
__device__ inline float tanhf_(float v) {
    v = fminf(fmaxf(v, -30.f), 30.f);
    float e = __expf(2.f * v);
    return (e - 1.f) / (e + 1.f);
}

// ---------------------------------------------------------------------------
// Combined prep: Wt gate-permuted bf16 (blocks [0,2048)) + Axh = bf16(x||h)
// (blocks [2048,6144), 4 rows each) + packed bias.  (unchanged, validated)
// ---------------------------------------------------------------------------
__global__ __launch_bounds__(256) void prep_all(
    const float* __restrict__ Wx, const float* __restrict__ Wh,
    const float* __restrict__ bx, const float* __restrict__ bh,
    const float* __restrict__ x,  const float* __restrict__ h,
    __hip_bfloat16* __restrict__ Wt, __hip_bfloat16* __restrict__ Axh,
    float* __restrict__ bias_p) {
    const int bid = blockIdx.x;
    const int t   = threadIdx.x;

    if (bid < 2048) {
        __shared__ __hip_bfloat16 tile[32][33];
        const int bk = bid & 31;
        const int bn = bid >> 5;
        const int kb = bk * 32, nb = bn * 32;
#pragma unroll
        for (int r = 0; r < 4; ++r) {
            int k_loc = r * 8 + (t >> 5);
            int n_loc = t & 31;
            int kg = kb + k_loc;
            float v = (kg < IN_DIM) ? Wx[(size_t)kg * N4H + nb + n_loc]
                                    : Wh[(size_t)(kg - IN_DIM) * N4H + nb + n_loc];
            tile[k_loc][n_loc] = __float2bfloat16(v);
        }
        __syncthreads();
        {
            int n_loc = t >> 3;
            int k_loc = (t & 7) * 4;
            int ng = nb + n_loc;
            int g  = ng >> 9;
            int c  = ng & 511;
            int row_out = (c >> 5) * 128 + g * 32 + (c & 31);
            short4v v4;
            v4.x = *reinterpret_cast<short*>(&tile[k_loc + 0][n_loc]);
            v4.y = *reinterpret_cast<short*>(&tile[k_loc + 1][n_loc]);
            v4.z = *reinterpret_cast<short*>(&tile[k_loc + 2][n_loc]);
            v4.w = *reinterpret_cast<short*>(&tile[k_loc + 3][n_loc]);
            *(short4v*)&Wt[(size_t)row_out * K_DIM + kb + k_loc] = v4;
        }
        if (bid < 8) {
            int ng = bid * 256 + t;
            int g  = ng >> 9;
            int c  = ng & 511;
            int ro = (c >> 5) * 128 + g * 32 + (c & 31);
            bias_p[ro] = bx[ng] + bh[ng];
        }
    } else {
        const int ab = bid - 2048;              // 0..4095, 4 rows each
        const int kq = t;                       // float4 index within row
        const float* src = (kq < 128) ? (x + kq * 4)
                                      : (h + (size_t)(kq - 128) * 4);
#pragma unroll
        for (int j = 0; j < 4; ++j) {
            int m = ab * 4 + j;
            float4 v = *(const float4*)(src + (size_t)m * 512);
            short4v sv;
            sv.x = bf16bits(v.x);
            sv.y = bf16bits(v.y);
            sv.z = bf16bits(v.z);
            sv.w = bf16bits(v.w);
            *(short4v*)&Axh[(size_t)m * K_DIM + kq * 4] = sv;
        }
    }
}

// ---------------------------------------------------------------------------
// Round 13: 256x256 tile, BK=32, 8 waves, 64KB LDS -> 2 resident blocks/CU
// = 16 waves/CU = 4 waves/SIMD (2x every prior round's latency hiding).
// r12 post-mortem refuted barrier-desync alone (2 clocks, same 2 waves/SIMD,
// no gain). All rounds plateau 26-31% MfmaUtil at 2 waves/SIMD; cycle ledger
// shows ~3000cy/tile of UNHIDDEN ds_read/DMA latency. This round doubles
// waves/SIMD while keeping r11's loop shape and per-wave read:MFMA ratio
// (12:32 == r11's 24:64):
//   per K-tile (32 of them): {12 ds_reads} -> {4 DMA stage t+1} ->
//     {32 MFMA, setprio} -> __syncthreads.  No asm waits, no sched pinning.
//   - grid 512 = 2 blocks/CU exactly co-resident; r7/r11-validated XCD
//     mapping (FETCH 66MB measured at this 256^2 tiling)
//   - LDS [dbuf][256 rows][32 k] per operand = 16KB/buf/op, 64KB total
//   - r0-validated additive-rotation swizzle (0 conflicts r4/r7/r8/r11/r12):
//     slot pg at row r holds k-octet (pg-(r>>1))&3; read slot
//     (quad+((r>>1)&3))&3.  Accumulation order = ascending k, unchanged.
//   - ni == gate -> thread-local LSTM epilogue (identical to r11)
// ---------------------------------------------------------------------------
__global__ __launch_bounds__(512, 4) void lstm_gemm256b(
    const float* __restrict__ c_in,
    const __hip_bfloat16* __restrict__ Axh,
    const __hip_bfloat16* __restrict__ Wt,
    const float* __restrict__ bias_p,
    float* __restrict__ out) {
    __shared__ __align__(16) __hip_bfloat16 lds_a[2][8192];   // 2 x 16KB
    __shared__ __align__(16) __hip_bfloat16 lds_b[2][8192];   // 2 x 16KB

    const int tid   = threadIdx.x;
    const int w     = tid >> 6;          // wave 0..7
    const int lane  = tid & 63;
    const int col16 = lane & 15;
    const int quad  = lane >> 4;
    const int wm    = w >> 2;            // 0..1  (M half: 128 rows)
    const int wn    = w & 3;             // 0..3  (N quarter: 16ch x 4 gates)

    // r7/r11-validated XCD-aware mapping (FETCH ~66MB): per-XCD 8bm x 8bn
    const int jb    = blockIdx.x;
    const int xcd   = jb & 7;
    const int local = jb >> 3;                   // 0..63
    const int bm    = xcd * 8 + (local >> 3);    // 0..63  (256 A rows each)
    const int bn    = local & 7;                 // 0..7   (256 Wt rows each)

    f32x4 acc[8][4];
#pragma unroll
    for (int mi = 0; mi < 8; ++mi)
#pragma unroll
        for (int ni = 0; ni < 4; ++ni)
            acc[mi][ni] = (f32x4){0.f, 0.f, 0.f, 0.f};

    const __hip_bfloat16* Ab = Axh + (size_t)bm * 256 * K_DIM;
    const __hip_bfloat16* Bb = Wt  + (size_t)bn * 256 * K_DIM;

    // staging: granule = j*512 + tid (16B) -> row j*128 + (tid>>2), phys slot
    // pg = tid&3 holds logical k-octet lq = (pg-(r>>1))&3 (inverse rotation).
    const int lq = ((tid & 3) - ((tid >> 3) & 3)) & 3;

    // one STAGE = one operand's full 256x32 K-slab (16KB): 2 issues/thread
#define STAGE(LDSBUF, GBASE, KT)  do {                                         \
    const __hip_bfloat16* _s = (GBASE) + (size_t)(tid >> 2) * K_DIM            \
                               + (KT) * 32 + lq * 8;                           \
    char* _d = (char*)(LDSBUF) + w * 1024;                                     \
    async_load16(_s,                       _d);                                \
    async_load16(_s + (size_t)128 * K_DIM, _d + 8192);                         \
  } while (0)

    // fragment-read byte offsets (validated rotation; rows 64B):
    // byte = r*64 + ((quad+((r>>1)&3))&3)*16
    int aoff[8], boff[4];
#pragma unroll
    for (int mi = 0; mi < 8; ++mi) {
        int r = wm * 128 + mi * 16 + col16;
        aoff[mi] = r * 64 + ((quad + ((r >> 1) & 3)) & 3) * 16;
    }
#pragma unroll
    for (int ni = 0; ni < 4; ++ni) {
        int r = (wn >> 1) * 128 + ni * 32 + (wn & 1) * 16 + col16;
        boff[ni] = r * 64 + ((quad + ((r >> 1) & 3)) & 3) * 16;
    }

    // prologue: stage K-tile 0 into buf 0, publish
    STAGE(lds_a[0], Ab, 0);
    STAGE(lds_b[0], Bb, 0);
    __syncthreads();

    for (int t = 0; t < 32; ++t) {
        const int cur = t & 1;
        const char* la = (const char*)lds_a[cur];
        const char* lb = (const char*)lds_b[cur];

        // 12 fragment reads (one BK=32 slab)
        short8 afr[8], bfr[4];
#pragma unroll
        for (int q = 0; q < 8; ++q) afr[q] = *(const short8*)(la + aoff[q]);
#pragma unroll
        for (int n = 0; n < 4; ++n) bfr[n] = *(const short8*)(lb + boff[n]);

        // stage tile t+1 (4 DMA issues/thread), drained by the closing
        // __syncthreads under the MFMA cover
        if (t < 31) {
            STAGE(lds_a[cur ^ 1], Ab, t + 1);
            STAGE(lds_b[cur ^ 1], Bb, t + 1);
        }

        __builtin_amdgcn_s_setprio(1);
#pragma unroll
        for (int q = 0; q < 8; ++q)
#pragma unroll
            for (int n = 0; n < 4; ++n)
                acc[q][n] = __builtin_amdgcn_mfma_f32_16x16x32_bf16(
                    afr[q], bfr[n], acc[q][n], 0, 0, 0);
        __builtin_amdgcn_s_setprio(0);

        __syncthreads();
    }
#undef STAGE

    // ---- fused LSTM epilogue (thread-local: ni == gate; identical to r11) --
    float bias_v[4];
#pragma unroll
    for (int g = 0; g < 4; ++g)
        bias_v[g] = bias_p[bn * 256 + (wn >> 1) * 128 + g * 32 + (wn & 1) * 16 + col16];

    const int hc_g = bn * 64 + (wn >> 1) * 32 + (wn & 1) * 16 + col16;

#pragma unroll
    for (int mi = 0; mi < 8; ++mi) {
#pragma unroll
        for (int reg = 0; reg < 4; ++reg) {
            const int m_g = bm * 256 + wm * 128 + mi * 16 + quad * 4 + reg;
            float gi = acc[mi][0][reg] + bias_v[0];
            float gf = acc[mi][1][reg] + bias_v[1];
            float gg = acc[mi][2][reg] + bias_v[2];
            float go = acc[mi][3][reg] + bias_v[3];
            float iv = sigmoidf_(gi);
            float fv = sigmoidf_(gf);
            float gv = tanhf_(gg);
            float ov = sigmoidf_(go);
            float co = c_in[(size_t)m_g * H_DIM + hc_g];
            float cn = fv * co + iv * gv;
            float hn = ov * tanhf_(cn);
            out[(size_t)m_g * H_DIM + hc_g]      = hn;   // h_new
            out[BH + (size_t)m_g * H_DIM + hc_g] = cn;   // c_new
        }
    }
}

// ---------------------------------------------------------------------------
// Fallback path (validated R1 kernels) in case ws_size < 36 MB.
// ---------------------------------------------------------------------------
__global__ __launch_bounds__(256) void prep_weights_fb(
    const float* __restrict__ Wx, const float* __restrict__ Wh,
    const float* __restrict__ bx, const float* __restrict__ bh,
    __hip_bfloat16* __restrict__ Wt, float* __restrict__ bias_p) {
    __shared__ __hip_bfloat16 tile[32][33];
    const int bid = blockIdx.x;
    const int bk  = bid & 31;
    const int bn  = bid >> 5;
    const int t   = threadIdx.x;
    const int kb  = bk * 32, nb = bn * 32;
#pragma unroll
    for (int r = 0; r < 4; ++r) {
        int k_loc = r * 8 + (t >> 5);
        int n_loc = t & 31;
        int kg = kb + k_loc;
        float v = (kg < IN_DIM) ? Wx[(size_t)kg * N4H + nb + n_loc]
                                : Wh[(size_t)(kg - IN_DIM) * N4H + nb + n_loc];
        tile[k_loc][n_loc] = __float2bfloat16(v);
    }
    __syncthreads();
    {
        int n_loc = t >> 3;
        int k_loc = (t & 7) * 4;
        int ng = nb + n_loc;
        int g  = ng >> 9;
        int c  = ng & 511;
        int row_out = (c >> 5) * 128 + g * 32 + (c & 31);
        short4v v4;
        v4.x = *reinterpret_cast<short*>(&tile[k_loc + 0][n_loc]);
        v4.y = *reinterpret_cast<short*>(&tile[k_loc + 1][n_loc]);
        v4.z = *reinterpret_cast<short*>(&tile[k_loc + 2][n_loc]);
        v4.w = *reinterpret_cast<short*>(&tile[k_loc + 3][n_loc]);
        *(short4v*)&Wt[(size_t)row_out * K_DIM + kb + k_loc] = v4;
    }
    if (bid < 8) {
        int ng = bid * 256 + t;
        int g  = ng >> 9;
        int c  = ng & 511;
        int ro = (c >> 5) * 128 + g * 32 + (c & 31);
        bias_p[ro] = bx[ng] + bh[ng];
    }
}

__global__ __launch_bounds__(256, 3) void lstm_gemm_fb(
    const float* __restrict__ x, const float* __restrict__ h,
    const float* __restrict__ c_in,
    const __hip_bfloat16* __restrict__ Wt, const float* __restrict__ bias_p,
    float* __restrict__ out) {
    __shared__ __hip_bfloat16 lds_a[128 * 32];
    __shared__ __hip_bfloat16 lds_b[128 * 32];
    const int tid   = threadIdx.x;
    const int bn    = blockIdx.x & 15;
    const int bm    = blockIdx.x >> 4;
    const int w     = tid >> 6;
    const int lane  = tid & 63;
    const int col16 = lane & 15;
    const int quad  = lane >> 4;
    f32x4 acc[2][8];
#pragma unroll
    for (int mi = 0; mi < 2; ++mi)
#pragma unroll
        for (int ni = 0; ni < 8; ++ni)
            acc[mi][ni] = (f32x4){0.f, 0.f, 0.f, 0.f};
    const __hip_bfloat16* wt_base = Wt + (size_t)(bn * 128) * K_DIM;
    const int chunk0 = w * 2;
    const int e0     = chunk0 * 512 + lane * 8;
    const int bn_loc0 = e0 >> 5, bk_off0 = e0 & 31;
    const int e1     = (chunk0 + 1) * 512 + lane * 8;
    const int bn_loc1 = e1 >> 5, bk_off1 = e1 & 31;
    for (int kt = 0; kt < 32; ++kt) {
        const int kb = kt * 32;
        const float* aptr;
        int koff;
        if (kb < IN_DIM) { aptr = x; koff = kb; }
        else             { aptr = h; koff = kb - IN_DIM; }
        async_load16(wt_base + (size_t)bn_loc0 * K_DIM + kb + bk_off0,
                     (void*)(lds_b + chunk0 * 512));
        async_load16(wt_base + (size_t)bn_loc1 * K_DIM + kb + bk_off1,
                     (void*)(lds_b + (chunk0 + 1) * 512));
        float4 av[4];
#pragma unroll
        for (int j = 0; j < 4; ++j) {
            int cch = j * 256 + tid;
            int row = cch >> 3;
            int kq  = (cch & 7) * 4;
            av[j] = *(const float4*)(aptr + (size_t)(bm * 128 + row) * IN_DIM
                                     + koff + kq);
        }
#pragma unroll
        for (int j = 0; j < 4; ++j) {
            int cch = j * 256 + tid;
            int row = cch >> 3;
            int kq  = (cch & 7) * 4;
            short4v sv;
            sv.x = bf16bits(av[j].x);
            sv.y = bf16bits(av[j].y);
            sv.z = bf16bits(av[j].z);
            sv.w = bf16bits(av[j].w);
            *(short4v*)&lds_a[row * 32 + kq] = sv;
        }
        __syncthreads();
        short8 afr[2], bfr[8];
#pragma unroll
        for (int mi = 0; mi < 2; ++mi)
            afr[mi] = *(const short8*)&lds_a[(w * 32 + mi * 16 + col16) * 32 + quad * 8];
#pragma unroll
        for (int ni = 0; ni < 8; ++ni)
            bfr[ni] = *(const short8*)&lds_b[(ni * 16 + col16) * 32 + quad * 8];
#pragma unroll
        for (int mi = 0; mi < 2; ++mi)
#pragma unroll
            for (int ni = 0; ni < 8; ++ni)
                acc[mi][ni] = __builtin_amdgcn_mfma_f32_16x16x32_bf16(
                    afr[mi], bfr[ni], acc[mi][ni], 0, 0, 0);
        __syncthreads();
    }
    float bias_v[4][2];
#pragma unroll
    for (int g = 0; g < 4; ++g)
#pragma unroll
        for (int h2 = 0; h2 < 2; ++h2)
            bias_v[g][h2] = bias_p[bn * 128 + g * 32 + h2 * 16 + col16];
#pragma unroll
    for (int mi = 0; mi < 2; ++mi) {
#pragma unroll
        for (int reg = 0; reg < 4; ++reg) {
            const int m_g = bm * 128 + w * 32 + mi * 16 + quad * 4 + reg;
#pragma unroll
            for (int h2 = 0; h2 < 2; ++h2) {
                const int hc_g = bn * 32 + h2 * 16 + col16;
                float gi = acc[mi][0 + h2][reg] + bias_v[0][h2];
                float gf = acc[mi][2 + h2][reg] + bias_v[1][h2];
                float gg = acc[mi][4 + h2][reg] + bias_v[2][h2];
                float go = acc[mi][6 + h2][reg] + bias_v[3][h2];
                float iv = sigmoidf_(gi);
                float fv = sigmoidf_(gf);
                float gv = tanhf_(gg);
                float ov = sigmoidf_(go);
                float co = c_in[(size_t)m_g * H_DIM + hc_g];
                float cn = fv * co + iv * gv;
                float hn = ov * tanhf_(cn);
                out[(size_t)m_g * H_DIM + hc_g]      = hn;
                out[BH + (size_t)m_g * H_DIM + hc_g] = cn;
            }
        }
    }
}

extern "C" void kernel_launch(void* const* d_in, const int* in_sizes, int n_in,
                              void* d_out, int out_size, void* d_ws, size_t ws_size,
                              hipStream_t stream) {
    const float* x  = (const float*)d_in[0];
    const float* h  = (const float*)d_in[1];
    const float* c  = (const float*)d_in[2];
    const float* Wx = (const float*)d_in[3];
    const float* Wh = (const float*)d_in[4];
    const float* bx = (const float*)d_in[5];
    const float* bh = (const float*)d_in[6];

    const size_t wtBytes  = (size_t)N4H * K_DIM * 2;    // 4 MB
    const size_t axhBytes = (size_t)B_DIM * K_DIM * 2;  // 32 MB
    const size_t need     = wtBytes + axhBytes + (size_t)N4H * 4;

    if (ws_size >= need) {
        __hip_bfloat16* Wt  = (__hip_bfloat16*)d_ws;
        __hip_bfloat16* Axh = (__hip_bfloat16*)((char*)d_ws + wtBytes);
        float* bias_p = (float*)((char*)d_ws + wtBytes + axhBytes);
        prep_all<<<6144, 256, 0, stream>>>(Wx, Wh, bx, bh, x, h, Wt, Axh, bias_p);
        lstm_gemm256b<<<512, 512, 0, stream>>>(c, Axh, Wt, bias_p, (float*)d_out);
    } else {
        __hip_bfloat16* Wt = (__hip_bfloat16*)d_ws;
        float* bias_p = (float*)((char*)d_ws + wtBytes);
        prep_weights_fb<<<2048, 256, 0, stream>>>(Wx, Wh, bx, bh, Wt, bias_p);
        lstm_gemm_fb<<<2048, 256, 0, stream>>>(x, h, c, Wt, bias_p, (float*)d_out);
    }
}

// Round 14
// 241.637 us; speedup vs baseline: 3.2261x; 3.2261x over previous
//
#include <hip/hip_runtime.h>
#include <hip/hip_bf16.h>

// Problem constants (fixed by the reference)
#define B_DIM   16384
#define IN_DIM  512
#define H_DIM   512
#define K_DIM   1024          // IN + H concatenated
#define N4H     2048          // 4*H
#define BH      (B_DIM * H_DIM)

typedef __attribute__((ext_vector_type(8))) short  short8;   // 8 bf16 = one MFMA operand
typedef __attribute__((ext_vector_type(4))) short  short4v;  // 4 bf16 = 8B write
typedef __attribute__((ext_vector_type(4))) float  f32x4;    // MFMA accumulator

__device__ inline void async_load16(const void* g, void* l) {
    __builtin_amdgcn_global_load_lds(
        (const __attribute__((address_space(1))) void*)g,
        (__attribute__((address_space(3)))       void*)l, 16, 0, 0);
}

__device__ inline short bf16bits(float f) {
    __hip_bfloat16 b = __float2bfloat16(f);
    return *reinterpret_cast<short*>(&b);
}

__device__ inline float sigmoidf_(float v) {
    return 1.0f / (1.0f + __expf(-v));
}
__device__ inline float tanhf_(float v) {
    v = fminf(fmaxf(v, -30.f), 30.f);
    float e = __expf(2.f * v);
    return (e - 1.f) / (e + 1.f);
}

// ---------------------------------------------------------------------------
// Combined prep: Wt gate-permuted bf16 (blocks [0,2048)) + Axh = bf16(x||h)
// (blocks [2048,6144), 4 rows each) + packed bias.  (unchanged, validated)
// ---------------------------------------------------------------------------
__global__ __launch_bounds__(256) void prep_all(
    const float* __restrict__ Wx, const float* __restrict__ Wh,
    const float* __restrict__ bx, const float* __restrict__ bh,
    const float* __restrict__ x,  const float* __restrict__ h,
    __hip_bfloat16* __restrict__ Wt, __hip_bfloat16* __restrict__ Axh,
    float* __restrict__ bias_p) {
    const int bid = blockIdx.x;
    const int t   = threadIdx.x;

    if (bid < 2048) {
        __shared__ __hip_bfloat16 tile[32][33];
        const int bk = bid & 31;
        const int bn = bid >> 5;
        const int kb = bk * 32, nb = bn * 32;
#pragma unroll
        for (int r = 0; r < 4; ++r) {
            int k_loc = r * 8 + (t >> 5);
            int n_loc = t & 31;
            int kg = kb + k_loc;
            float v = (kg < IN_DIM) ? Wx[(size_t)kg * N4H + nb + n_loc]
                                    : Wh[(size_t)(kg - IN_DIM) * N4H + nb + n_loc];
            tile[k_loc][n_loc] = __float2bfloat16(v);
        }
        __syncthreads();
        {
            int n_loc = t >> 3;
            int k_loc = (t & 7) * 4;
            int ng = nb + n_loc;
            int g  = ng >> 9;
            int c  = ng & 511;
            int row_out = (c >> 5) * 128 + g * 32 + (c & 31);
            short4v v4;
            v4.x = *reinterpret_cast<short*>(&tile[k_loc + 0][n_loc]);
            v4.y = *reinterpret_cast<short*>(&tile[k_loc + 1][n_loc]);
            v4.z = *reinterpret_cast<short*>(&tile[k_loc + 2][n_loc]);
            v4.w = *reinterpret_cast<short*>(&tile[k_loc + 3][n_loc]);
            *(short4v*)&Wt[(size_t)row_out * K_DIM + kb + k_loc] = v4;
        }
        if (bid < 8) {
            int ng = bid * 256 + t;
            int g  = ng >> 9;
            int c  = ng & 511;
            int ro = (c >> 5) * 128 + g * 32 + (c & 31);
            bias_p[ro] = bx[ng] + bh[ng];
        }
    } else {
        const int ab = bid - 2048;              // 0..4095, 4 rows each
        const int kq = t;                       // float4 index within row
        const float* src = (kq < 128) ? (x + kq * 4)
                                      : (h + (size_t)(kq - 128) * 4);
#pragma unroll
        for (int j = 0; j < 4; ++j) {
            int m = ab * 4 + j;
            float4 v = *(const float4*)(src + (size_t)m * 512);
            short4v sv;
            sv.x = bf16bits(v.x);
            sv.y = bf16bits(v.y);
            sv.z = bf16bits(v.z);
            sv.w = bf16bits(v.w);
            *(short4v*)&Axh[(size_t)m * K_DIM + kq * 4] = sv;
        }
    }
}

// ---------------------------------------------------------------------------
// Round 14: the REAL 4-waves/SIMD test (r13 spilled: launch_bounds(512,4)
// capped VGPR at 128 < acc[8][4]'s 128+overhead -> 1.96GB scratch writes,
// MfmaUtil 4%). This config fits: 128x128 tile, 4 waves, wave tile 64x64 ->
// acc[4][4]=64 VGPRs; r12's near-identical wave structure measured 88 VGPR,
// well under the 128 cap of __launch_bounds__(256,4).
//   - BK=32 double-buffered: LDS = 2 x (128x32) x 2 ops x 2B = 32KB
//     -> 4 blocks/CU = 16 waves/CU = 4 waves/SIMD (2x all prior rounds)
//   - r11's loop shape: {8 ds_reads} -> {4 DMA stage t+1} -> {16 MFMA,
//     setprio} -> __syncthreads. No asm waits, no sched pinning.
//   - grid 2048, r0/r12 XCD mapping; validated rotation swizzle (0 conflicts
//     r4/r7/r8/r11/r12); ascending-k accumulation (numerics unchanged)
//   - ni == gate -> thread-local LSTM epilogue (identical to r12)
// Spill tripwire: WRITE_SIZE should stay ~65.5MB; >> that means spill.
// ---------------------------------------------------------------------------
__global__ __launch_bounds__(256, 4) void lstm_gemm128q(
    const float* __restrict__ c_in,
    const __hip_bfloat16* __restrict__ Axh,
    const __hip_bfloat16* __restrict__ Wt,
    const float* __restrict__ bias_p,
    float* __restrict__ out) {
    __shared__ __align__(16) __hip_bfloat16 lds_a[2][4096];   // 2 x 8KB
    __shared__ __align__(16) __hip_bfloat16 lds_b[2][4096];   // 2 x 8KB

    const int tid   = threadIdx.x;
    const int w     = tid >> 6;          // wave 0..3
    const int lane  = tid & 63;
    const int col16 = lane & 15;
    const int quad  = lane >> 4;
    const int wm    = w >> 1;            // 0..1  (M half: 64 rows)
    const int wnn   = w & 1;             // 0..1  (channel half: 16 ch)

    // r0/r12 XCD-aware mapping
    const int jb    = blockIdx.x;
    const int xcd   = jb & 7;
    const int local = jb >> 3;                   // 0..255
    const int bm    = xcd * 16 + (local >> 4);   // 0..127 (128 A rows each)
    const int bn    = local & 15;                // 0..15  (128 Wt rows each)

    f32x4 acc[4][4];
#pragma unroll
    for (int mi = 0; mi < 4; ++mi)
#pragma unroll
        for (int ni = 0; ni < 4; ++ni)
            acc[mi][ni] = (f32x4){0.f, 0.f, 0.f, 0.f};

    const __hip_bfloat16* Ab = Axh + (size_t)bm * 128 * K_DIM;
    const __hip_bfloat16* Bb = Wt  + (size_t)bn * 128 * K_DIM;

    // staging: issue j covers rows j*64 + (tid>>2); phys slot pg = tid&3
    // holds logical k-octet lq = (pg-(r>>1))&3  ((r>>1)&3 == (tid>>3)&3).
    const int lq = ((tid & 3) - ((tid >> 3) & 3)) & 3;

    // one STAGE = one operand's 128x32 K-slab (8KB): 2 issues/thread
#define STAGE(LDSBUF, GBASE, KT)  do {                                         \
    const __hip_bfloat16* _s = (GBASE) + (size_t)(tid >> 2) * K_DIM            \
                               + (KT) * 32 + lq * 8;                           \
    char* _d = (char*)(LDSBUF) + w * 1024;                                     \
    async_load16(_s,                      _d);                                 \
    async_load16(_s + (size_t)64 * K_DIM, _d + 4096);                          \
  } while (0)

    // fragment-read byte offsets (validated rotation; rows 64B = 32 bf16):
    // byte = r*64 + ((quad+((r>>1)&3))&3)*16
    int aoff[4], boff[4];
#pragma unroll
    for (int mi = 0; mi < 4; ++mi) {
        int r = wm * 64 + mi * 16 + col16;
        aoff[mi] = r * 64 + ((quad + ((r >> 1) & 3)) & 3) * 16;
    }
#pragma unroll
    for (int ni = 0; ni < 4; ++ni) {
        int r = ni * 32 + wnn * 16 + col16;
        boff[ni] = r * 64 + ((quad + ((r >> 1) & 3)) & 3) * 16;
    }

    // prologue: stage K-tile 0 into buf 0, publish
    STAGE(lds_a[0], Ab, 0);
    STAGE(lds_b[0], Bb, 0);
    __syncthreads();

    for (int t = 0; t < 32; ++t) {
        const int cur = t & 1;
        const char* la = (const char*)lds_a[cur];
        const char* lb = (const char*)lds_b[cur];

        // 8 fragment reads (one BK=32 slab)
        short8 afr[4], bfr[4];
#pragma unroll
        for (int q = 0; q < 4; ++q) afr[q] = *(const short8*)(la + aoff[q]);
#pragma unroll
        for (int n = 0; n < 4; ++n) bfr[n] = *(const short8*)(lb + boff[n]);

        // stage tile t+1 (4 DMA issues/thread), drained by the closing
        // __syncthreads under the MFMA cover
        if (t < 31) {
            STAGE(lds_a[cur ^ 1], Ab, t + 1);
            STAGE(lds_b[cur ^ 1], Bb, t + 1);
        }

        __builtin_amdgcn_s_setprio(1);
#pragma unroll
        for (int q = 0; q < 4; ++q)
#pragma unroll
            for (int n = 0; n < 4; ++n)
                acc[q][n] = __builtin_amdgcn_mfma_f32_16x16x32_bf16(
                    afr[q], bfr[n], acc[q][n], 0, 0, 0);
        __builtin_amdgcn_s_setprio(0);

        __syncthreads();
    }
#undef STAGE

    // ---- fused LSTM epilogue (thread-local: ni == gate; identical to r12) --
    float bias_v[4];
#pragma unroll
    for (int g = 0; g < 4; ++g)
        bias_v[g] = bias_p[bn * 128 + g * 32 + wnn * 16 + col16];

    const int hc_g = bn * 32 + wnn * 16 + col16;

#pragma unroll
    for (int mi = 0; mi < 4; ++mi) {
#pragma unroll
        for (int reg = 0; reg < 4; ++reg) {
            const int m_g = bm * 128 + wm * 64 + mi * 16 + quad * 4 + reg;
            float gi = acc[mi][0][reg] + bias_v[0];
            float gf = acc[mi][1][reg] + bias_v[1];
            float gg = acc[mi][2][reg] + bias_v[2];
            float go = acc[mi][3][reg] + bias_v[3];
            float iv = sigmoidf_(gi);
            float fv = sigmoidf_(gf);
            float gv = tanhf_(gg);
            float ov = sigmoidf_(go);
            float co = c_in[(size_t)m_g * H_DIM + hc_g];
            float cn = fv * co + iv * gv;
            float hn = ov * tanhf_(cn);
            out[(size_t)m_g * H_DIM + hc_g]      = hn;   // h_new
            out[BH + (size_t)m_g * H_DIM + hc_g] = cn;   // c_new
        }
    }
}

// ---------------------------------------------------------------------------
// Fallback path (validated R1 kernels) in case ws_size < 36 MB.
// ---------------------------------------------------------------------------
__global__ __launch_bounds__(256) void prep_weights_fb(
    const float* __restrict__ Wx, const float* __restrict__ Wh,
    const float* __restrict__ bx, const float* __restrict__ bh,
    __hip_bfloat16* __restrict__ Wt, float* __restrict__ bias_p) {
    __shared__ __hip_bfloat16 tile[32][33];
    const int bid = blockIdx.x;
    const int bk  = bid & 31;
    const int bn  = bid >> 5;
    const int t   = threadIdx.x;
    const int kb  = bk * 32, nb = bn * 32;
#pragma unroll
    for (int r = 0; r < 4; ++r) {
        int k_loc = r * 8 + (t >> 5);
        int n_loc = t & 31;
        int kg = kb + k_loc;
        float v = (kg < IN_DIM) ? Wx[(size_t)kg * N4H + nb + n_loc]
                                : Wh[(size_t)(kg - IN_DIM) * N4H + nb + n_loc];
        tile[k_loc][n_loc] = __float2bfloat16(v);
    }
    __syncthreads();
    {
        int n_loc = t >> 3;
        int k_loc = (t & 7) * 4;
        int ng = nb + n_loc;
        int g  = ng >> 9;
        int c  = ng & 511;
        int row_out = (c >> 5) * 128 + g * 32 + (c & 31);
        short4v v4;
        v4.x = *reinterpret_cast<short*>(&tile[k_loc + 0][n_loc]);
        v4.y = *reinterpret_cast<short*>(&tile[k_loc + 1][n_loc]);
        v4.z = *reinterpret_cast<short*>(&tile[k_loc + 2][n_loc]);
        v4.w = *reinterpret_cast<short*>(&tile[k_loc + 3][n_loc]);
        *(short4v*)&Wt[(size_t)row_out * K_DIM + kb + k_loc] = v4;
    }
    if (bid < 8) {
        int ng = bid * 256 + t;
        int g  = ng >> 9;
        int c  = ng & 511;
        int ro = (c >> 5) * 128 + g * 32 + (c & 31);
        bias_p[ro] = bx[ng] + bh[ng];
    }
}

__global__ __launch_bounds__(256, 3) void lstm_gemm_fb(
    const float* __restrict__ x, const float* __restrict__ h,
    const float* __restrict__ c_in,
    const __hip_bfloat16* __restrict__ Wt, const float* __restrict__ bias_p,
    float* __restrict__ out) {
    __shared__ __hip_bfloat16 lds_a[128 * 32];
    __shared__ __hip_bfloat16 lds_b[128 * 32];
    const int tid   = threadIdx.x;
    const int bn    = blockIdx.x & 15;
    const int bm    = blockIdx.x >> 4;
    const int w     = tid >> 6;
    const int lane  = tid & 63;
    const int col16 = lane & 15;
    const int quad  = lane >> 4;
    f32x4 acc[2][8];
#pragma unroll
    for (int mi = 0; mi < 2; ++mi)
#pragma unroll
        for (int ni = 0; ni < 8; ++ni)
            acc[mi][ni] = (f32x4){0.f, 0.f, 0.f, 0.f};
    const __hip_bfloat16* wt_base = Wt + (size_t)(bn * 128) * K_DIM;
    const int chunk0 = w * 2;
    const int e0     = chunk0 * 512 + lane * 8;
    const int bn_loc0 = e0 >> 5, bk_off0 = e0 & 31;
    const int e1     = (chunk0 + 1) * 512 + lane * 8;
    const int bn_loc1 = e1 >> 5, bk_off1 = e1 & 31;
    for (int kt = 0; kt < 32; ++kt) {
        const int kb = kt * 32;
        const float* aptr;
        int koff;
        if (kb < IN_DIM) { aptr = x; koff = kb; }
        else             { aptr = h; koff = kb - IN_DIM; }
        async_load16(wt_base + (size_t)bn_loc0 * K_DIM + kb + bk_off0,
                     (void*)(lds_b + chunk0 * 512));
        async_load16(wt_base + (size_t)bn_loc1 * K_DIM + kb + bk_off1,
                     (void*)(lds_b + (chunk0 + 1) * 512));
        float4 av[4];
#pragma unroll
        for (int j = 0; j < 4; ++j) {
            int cch = j * 256 + tid;
            int row = cch >> 3;
            int kq  = (cch & 7) * 4;
            av[j] = *(const float4*)(aptr + (size_t)(bm * 128 + row) * IN_DIM
                                     + koff + kq);
        }
#pragma unroll
        for (int j = 0; j < 4; ++j) {
            int cch = j * 256 + tid;
            int row = cch >> 3;
            int kq  = (cch & 7) * 4;
            short4v sv;
            sv.x = bf16bits(av[j].x);
            sv.y = bf16bits(av[j].y);
            sv.z = bf16bits(av[j].z);
            sv.w = bf16bits(av[j].w);
            *(short4v*)&lds_a[row * 32 + kq] = sv;
        }
        __syncthreads();
        short8 afr[2], bfr[8];
#pragma unroll
        for (int mi = 0; mi < 2; ++mi)
            afr[mi] = *(const short8*)&lds_a[(w * 32 + mi * 16 + col16) * 32 + quad * 8];
#pragma unroll
        for (int ni = 0; ni < 8; ++ni)
            bfr[ni] = *(const short8*)&lds_b[(ni * 16 + col16) * 32 + quad * 8];
#pragma unroll
        for (int mi = 0; mi < 2; ++mi)
#pragma unroll
            for (int ni = 0; ni < 8; ++ni)
                acc[mi][ni] = __builtin_amdgcn_mfma_f32_16x16x32_bf16(
                    afr[mi], bfr[ni], acc[mi][ni], 0, 0, 0);
        __syncthreads();
    }
    float bias_v[4][2];
#pragma unroll
    for (int g = 0; g < 4; ++g)
#pragma unroll
        for (int h2 = 0; h2 < 2; ++h2)
            bias_v[g][h2] = bias_p[bn * 128 + g * 32 + h2 * 16 + col16];
#pragma unroll
    for (int mi = 0; mi < 2; ++mi) {
#pragma unroll
        for (int reg = 0; reg < 4; ++reg) {
            const int m_g = bm * 128 + w * 32 + mi * 16 + quad * 4 + reg;
#pragma unroll
            for (int h2 = 0; h2 < 2; ++h2) {
                const int hc_g = bn * 32 + h2 * 16 + col16;
                float gi = acc[mi][0 + h2][reg] + bias_v[0][h2];
                float gf = acc[mi][2 + h2][reg] + bias_v[1][h2];
                float gg = acc[mi][4 + h2][reg] + bias_v[2][h2];
                float go = acc[mi][6 + h2][reg] + bias_v[3][h2];
                float iv = sigmoidf_(gi);
                float fv = sigmoidf_(gf);
                float gv = tanhf_(gg);
                float ov = sigmoidf_(go);
                float co = c_in[(size_t)m_g * H_DIM + hc_g];
                float cn = fv * co + iv * gv;
                float hn = ov * tanhf_(cn);
                out[(size_t)m_g * H_DIM + hc_g]      = hn;
                out[BH + (size_t)m_g * H_DIM + hc_g] = cn;
            }
        }
    }
}

extern "C" void kernel_launch(void* const* d_in, const int* in_sizes, int n_in,
                              void* d_out, int out_size, void* d_ws, size_t ws_size,
                              hipStream_t stream) {
    const float* x  = (const float*)d_in[0];
    const float* h  = (const float*)d_in[1];
    const float* c  = (const float*)d_in[2];
    const float* Wx = (const float*)d_in[3];
    const float* Wh = (const float*)d_in[4];
    const float* bx = (const float*)d_in[5];
    const float* bh = (const float*)d_in[6];

    const size_t wtBytes  = (size_t)N4H * K_DIM * 2;    // 4 MB
    const size_t axhBytes = (size_t)B_DIM * K_DIM * 2;  // 32 MB
    const size_t need     = wtBytes + axhBytes + (size_t)N4H * 4;

    if (ws_size >= need) {
        __hip_bfloat16* Wt  = (__hip_bfloat16*)d_ws;
        __hip_bfloat16* Axh = (__hip_bfloat16*)((char*)d_ws + wtBytes);
        float* bias_p = (float*)((char*)d_ws + wtBytes + axhBytes);
        prep_all<<<6144, 256, 0, stream>>>(Wx, Wh, bx, bh, x, h, Wt, Axh, bias_p);
        lstm_gemm128q<<<2048, 256, 0, stream>>>(c, Axh, Wt, bias_p, (float*)d_out);
    } else {
        __hip_bfloat16* Wt = (__hip_bfloat16*)d_ws;
        float* bias_p = (float*)((char*)d_ws + wtBytes);
        prep_weights_fb<<<2048, 256, 0, stream>>>(Wx, Wh, bx, bh, Wt, bias_p);
        lstm_gemm_fb<<<2048, 256, 0, stream>>>(x, h, c, Wt, bias_p, (float*)d_out);
    }
}

// Round 15
// 229.535 us; speedup vs baseline: 3.3962x; 1.0527x over previous
//
#include <hip/hip_runtime.h>
#include <hip/hip_bf16.h>

// Problem constants (fixed by the reference)
#define B_DIM   16384
#define IN_DIM  512
#define H_DIM   512
#define K_DIM   1024          // IN + H concatenated
#define N4H     2048          // 4*H
#define BH      (B_DIM * H_DIM)

typedef __attribute__((ext_vector_type(8))) short  short8;   // 8 bf16 = one MFMA operand
typedef __attribute__((ext_vector_type(4))) short  short4v;  // 4 bf16 = 8B write
typedef __attribute__((ext_vector_type(4))) float  f32x4;    // MFMA accumulator

__device__ inline void async_load16(const void* g, void* l) {
    __builtin_amdgcn_global_load_lds(
        (const __attribute__((address_space(1))) void*)g,
        (__attribute__((address_space(3)))       void*)l, 16, 0, 0);
}

__device__ inline short bf16bits(float f) {
    __hip_bfloat16 b = __float2bfloat16(f);
    return *reinterpret_cast<short*>(&b);
}

__device__ inline float sigmoidf_(float v) {
    return 1.0f / (1.0f + __expf(-v));
}
__device__ inline float tanhf_(float v) {
    v = fminf(fmaxf(v, -30.f), 30.f);
    float e = __expf(2.f * v);
    return (e - 1.f) / (e + 1.f);
}

// ---------------------------------------------------------------------------
// Combined prep: Wt gate-permuted bf16 (blocks [0,2048)) + Axh = bf16(x||h)
// (blocks [2048,6144), 4 rows each) + packed bias.  (validated)
// ---------------------------------------------------------------------------
__global__ __launch_bounds__(256) void prep_all(
    const float* __restrict__ Wx, const float* __restrict__ Wh,
    const float* __restrict__ bx, const float* __restrict__ bh,
    const float* __restrict__ x,  const float* __restrict__ h,
    __hip_bfloat16* __restrict__ Wt, __hip_bfloat16* __restrict__ Axh,
    float* __restrict__ bias_p) {
    const int bid = blockIdx.x;
    const int t   = threadIdx.x;

    if (bid < 2048) {
        __shared__ __hip_bfloat16 tile[32][33];
        const int bk = bid & 31;
        const int bn = bid >> 5;
        const int kb = bk * 32, nb = bn * 32;
#pragma unroll
        for (int r = 0; r < 4; ++r) {
            int k_loc = r * 8 + (t >> 5);
            int n_loc = t & 31;
            int kg = kb + k_loc;
            float v = (kg < IN_DIM) ? Wx[(size_t)kg * N4H + nb + n_loc]
                                    : Wh[(size_t)(kg - IN_DIM) * N4H + nb + n_loc];
            tile[k_loc][n_loc] = __float2bfloat16(v);
        }
        __syncthreads();
        {
            int n_loc = t >> 3;
            int k_loc = (t & 7) * 4;
            int ng = nb + n_loc;
            int g  = ng >> 9;
            int c  = ng & 511;
            int row_out = (c >> 5) * 128 + g * 32 + (c & 31);
            short4v v4;
            v4.x = *reinterpret_cast<short*>(&tile[k_loc + 0][n_loc]);
            v4.y = *reinterpret_cast<short*>(&tile[k_loc + 1][n_loc]);
            v4.z = *reinterpret_cast<short*>(&tile[k_loc + 2][n_loc]);
            v4.w = *reinterpret_cast<short*>(&tile[k_loc + 3][n_loc]);
            *(short4v*)&Wt[(size_t)row_out * K_DIM + kb + k_loc] = v4;
        }
        if (bid < 8) {
            int ng = bid * 256 + t;
            int g  = ng >> 9;
            int c  = ng & 511;
            int ro = (c >> 5) * 128 + g * 32 + (c & 31);
            bias_p[ro] = bx[ng] + bh[ng];
        }
    } else {
        const int ab = bid - 2048;              // 0..4095, 4 rows each
        const int kq = t;                       // float4 index within row
        const float* src = (kq < 128) ? (x + kq * 4)
                                      : (h + (size_t)(kq - 128) * 4);
#pragma unroll
        for (int j = 0; j < 4; ++j) {
            int m = ab * 4 + j;
            float4 v = *(const float4*)(src + (size_t)m * 512);
            short4v sv;
            sv.x = bf16bits(v.x);
            sv.y = bf16bits(v.y);
            sv.z = bf16bits(v.z);
            sv.w = bf16bits(v.w);
            *(short4v*)&Axh[(size_t)m * K_DIM + kq * 4] = sv;
        }
    }
}

// ---------------------------------------------------------------------------
// FINAL (= round 11, best measured: gemm 94.2us, total 224.3us).
// ILP-overlapped 256x256 GEMM + fused LSTM epilogue.
// Session ledger: six structurally distinct schedules (2-barrier 128², 4-phase
// counted vmcnt, 2-phase counted, this ILP form, 2-block desync, 4-waves/SIMD
// BK=32) all plateau at 94-110us / MfmaUtil 26-31% with conflicts=0, no
// spill, FETCH minimal — plateau is structural for this N=2048/K=1024 shape.
//   per K-tile: {24 ds_reads: ph0 frags then ph1 frags} -> {8 gload_lds for
//   tile t+1} -> MFMA ph0 -> MFMA ph1 -> __syncthreads (vmcnt0+lgkm0+barrier
//   = exact tile-boundary semantics; DMA has ~2500cy MFMA cover).
//   No inline-asm waits, no sched_barriers: compiler schedules freely.
//   - 512 blocks, XCD mapping (r7/r11-validated, FETCH 66MB)
//   - LDS [dbuf][kh][256r][32k] per array = 128KB; validated additive
//     rotation swizzle (0 conflicts r4/r7/r8/r11/r12/r14), pre-swizzled
//     global source, linear DMA dest; ascending-k accumulation order.
//   - ni == gate -> thread-local LSTM epilogue.
// ---------------------------------------------------------------------------
__global__ __launch_bounds__(512, 2) void lstm_gemm256(
    const float* __restrict__ c_in,
    const __hip_bfloat16* __restrict__ Axh,
    const __hip_bfloat16* __restrict__ Wt,
    const float* __restrict__ bias_p,
    float* __restrict__ out) {
    __shared__ __align__(16) __hip_bfloat16 lds_a[2][16384];  // [dbuf][kh*8192+..]
    __shared__ __align__(16) __hip_bfloat16 lds_b[2][16384];

    const int tid   = threadIdx.x;
    const int w     = tid >> 6;          // wave 0..7
    const int lane  = tid & 63;
    const int col16 = lane & 15;
    const int quad  = lane >> 4;
    const int wm    = w >> 2;            // 0..1  (M half: 128 rows)
    const int wn    = w & 3;             // 0..3  (N quarter: 16ch x 4 gates)

    // r7/r11-validated XCD-aware mapping (FETCH ~66MB): per-XCD 8bm x 8bn
    const int jb    = blockIdx.x;
    const int xcd   = jb & 7;
    const int local = jb >> 3;                   // 0..63
    const int bm    = xcd * 8 + (local >> 3);    // 0..63  (256 A rows each)
    const int bn    = local & 7;                 // 0..7   (256 Wt rows each)

    f32x4 acc[8][4];
#pragma unroll
    for (int mi = 0; mi < 8; ++mi)
#pragma unroll
        for (int ni = 0; ni < 4; ++ni)
            acc[mi][ni] = (f32x4){0.f, 0.f, 0.f, 0.f};

    const __hip_bfloat16* Ab = Axh + (size_t)bm * 256 * K_DIM;
    const __hip_bfloat16* Bb = Wt  + (size_t)bn * 256 * K_DIM;

    // staging: granule = j*512 + tid (16B) -> row j*128 + (tid>>2), phys slot
    // pg = tid&3 holds logical k-octet lq = (pg-(r>>1))&3 (inverse rotation).
    const int lq = ((tid & 3) - ((tid >> 3) & 3)) & 3;

#define STAGE(LDSBUF, GBASE, KH, KT)  do {                                     \
    const __hip_bfloat16* _s = (GBASE) + (size_t)(tid >> 2) * K_DIM            \
                               + (KT) * 64 + (KH) * 32 + lq * 8;               \
    char* _d = (char*)(LDSBUF) + (KH) * 16384 + w * 1024;                      \
    async_load16(_s,                       _d);                                \
    async_load16(_s + (size_t)128 * K_DIM, _d + 8192);                         \
  } while (0)

    // fragment-read byte offsets (validated rotation, 0 conflicts):
    // byte = r*64 + ((quad+((r>>1)&3))&3)*16 within kh-block; kh adds 16384.
    int aoff[8], boff[4];
#pragma unroll
    for (int mi = 0; mi < 8; ++mi) {
        int r = wm * 128 + mi * 16 + col16;
        aoff[mi] = r * 64 + ((quad + ((r >> 1) & 3)) & 3) * 16;
    }
#pragma unroll
    for (int ni = 0; ni < 4; ++ni) {
        int r = (wn >> 1) * 128 + ni * 32 + (wn & 1) * 16 + col16;
        boff[ni] = r * 64 + ((quad + ((r >> 1) & 3)) & 3) * 16;
    }

    // prologue: stage tile 0 into buf 0, publish
    STAGE(lds_a[0], Ab, 0, 0);
    STAGE(lds_b[0], Bb, 0, 0);
    STAGE(lds_a[0], Ab, 1, 0);
    STAGE(lds_b[0], Bb, 1, 0);
    __syncthreads();

    for (int t = 0; t < 16; ++t) {
        const int cur = t & 1;
        const char* la = (const char*)lds_a[cur];
        const char* lb = (const char*)lds_b[cur];
        __hip_bfloat16* nxa = lds_a[cur ^ 1];
        __hip_bfloat16* nxb = lds_b[cur ^ 1];

        // all 24 fragment reads up front: ph0 (kh0) first, ph1 (kh1) second.
        short8 a0[8], b0[4], a1[8], b1[4];
#pragma unroll
        for (int q = 0; q < 8; ++q) a0[q] = *(const short8*)(la + aoff[q]);
#pragma unroll
        for (int n = 0; n < 4; ++n) b0[n] = *(const short8*)(lb + boff[n]);
#pragma unroll
        for (int q = 0; q < 8; ++q) a1[q] = *(const short8*)(la + 16384 + aoff[q]);
#pragma unroll
        for (int n = 0; n < 4; ++n) b1[n] = *(const short8*)(lb + 16384 + boff[n]);

        // stage tile t+1 (8 DMA loads) — drained by this iteration's closing
        // __syncthreads, with the full MFMA region (~2500cy) as cover.
        if (t < 15) {
            STAGE(nxa, Ab, 0, t + 1);
            STAGE(nxb, Bb, 0, t + 1);
            STAGE(nxa, Ab, 1, t + 1);
            STAGE(nxb, Bb, 1, t + 1);
        }

        // MFMA ph0 then ph1 (fine lgkmcnt inserted by the compiler)
        __builtin_amdgcn_s_setprio(1);
#pragma unroll
        for (int q = 0; q < 8; ++q)
#pragma unroll
            for (int n = 0; n < 4; ++n)
                acc[q][n] = __builtin_amdgcn_mfma_f32_16x16x32_bf16(
                    a0[q], b0[n], acc[q][n], 0, 0, 0);
#pragma unroll
        for (int q = 0; q < 8; ++q)
#pragma unroll
            for (int n = 0; n < 4; ++n)
                acc[q][n] = __builtin_amdgcn_mfma_f32_16x16x32_bf16(
                    a1[q], b1[n], acc[q][n], 0, 0, 0);
        __builtin_amdgcn_s_setprio(0);

        // tile boundary: vmcnt(0)+lgkmcnt(0)+barrier (exact semantics needed)
        __syncthreads();
    }
#undef STAGE

    // ---- fused LSTM epilogue (thread-local: ni == gate) ----
    float bias_v[4];
#pragma unroll
    for (int g = 0; g < 4; ++g)
        bias_v[g] = bias_p[bn * 256 + (wn >> 1) * 128 + g * 32 + (wn & 1) * 16 + col16];

    const int hc_g = bn * 64 + (wn >> 1) * 32 + (wn & 1) * 16 + col16;

#pragma unroll
    for (int mi = 0; mi < 8; ++mi) {
#pragma unroll
        for (int reg = 0; reg < 4; ++reg) {
            const int m_g = bm * 256 + wm * 128 + mi * 16 + quad * 4 + reg;
            float gi = acc[mi][0][reg] + bias_v[0];
            float gf = acc[mi][1][reg] + bias_v[1];
            float gg = acc[mi][2][reg] + bias_v[2];
            float go = acc[mi][3][reg] + bias_v[3];
            float iv = sigmoidf_(gi);
            float fv = sigmoidf_(gf);
            float gv = tanhf_(gg);
            float ov = sigmoidf_(go);
            float co = c_in[(size_t)m_g * H_DIM + hc_g];
            float cn = fv * co + iv * gv;
            float hn = ov * tanhf_(cn);
            out[(size_t)m_g * H_DIM + hc_g]      = hn;   // h_new
            out[BH + (size_t)m_g * H_DIM + hc_g] = cn;   // c_new
        }
    }
}

// ---------------------------------------------------------------------------
// Fallback path (validated R1 kernels) in case ws_size < 36 MB.
// ---------------------------------------------------------------------------
__global__ __launch_bounds__(256) void prep_weights_fb(
    const float* __restrict__ Wx, const float* __restrict__ Wh,
    const float* __restrict__ bx, const float* __restrict__ bh,
    __hip_bfloat16* __restrict__ Wt, float* __restrict__ bias_p) {
    __shared__ __hip_bfloat16 tile[32][33];
    const int bid = blockIdx.x;
    const int bk  = bid & 31;
    const int bn  = bid >> 5;
    const int t   = threadIdx.x;
    const int kb  = bk * 32, nb = bn * 32;
#pragma unroll
    for (int r = 0; r < 4; ++r) {
        int k_loc = r * 8 + (t >> 5);
        int n_loc = t & 31;
        int kg = kb + k_loc;
        float v = (kg < IN_DIM) ? Wx[(size_t)kg * N4H + nb + n_loc]
                                : Wh[(size_t)(kg - IN_DIM) * N4H + nb + n_loc];
        tile[k_loc][n_loc] = __float2bfloat16(v);
    }
    __syncthreads();
    {
        int n_loc = t >> 3;
        int k_loc = (t & 7) * 4;
        int ng = nb + n_loc;
        int g  = ng >> 9;
        int c  = ng & 511;
        int row_out = (c >> 5) * 128 + g * 32 + (c & 31);
        short4v v4;
        v4.x = *reinterpret_cast<short*>(&tile[k_loc + 0][n_loc]);
        v4.y = *reinterpret_cast<short*>(&tile[k_loc + 1][n_loc]);
        v4.z = *reinterpret_cast<short*>(&tile[k_loc + 2][n_loc]);
        v4.w = *reinterpret_cast<short*>(&tile[k_loc + 3][n_loc]);
        *(short4v*)&Wt[(size_t)row_out * K_DIM + kb + k_loc] = v4;
    }
    if (bid < 8) {
        int ng = bid * 256 + t;
        int g  = ng >> 9;
        int c  = ng & 511;
        int ro = (c >> 5) * 128 + g * 32 + (c & 31);
        bias_p[ro] = bx[ng] + bh[ng];
    }
}

__global__ __launch_bounds__(256, 3) void lstm_gemm_fb(
    const float* __restrict__ x, const float* __restrict__ h,
    const float* __restrict__ c_in,
    const __hip_bfloat16* __restrict__ Wt, const float* __restrict__ bias_p,
    float* __restrict__ out) {
    __shared__ __hip_bfloat16 lds_a[128 * 32];
    __shared__ __hip_bfloat16 lds_b[128 * 32];
    const int tid   = threadIdx.x;
    const int bn    = blockIdx.x & 15;
    const int bm    = blockIdx.x >> 4;
    const int w     = tid >> 6;
    const int lane  = tid & 63;
    const int col16 = lane & 15;
    const int quad  = lane >> 4;
    f32x4 acc[2][8];
#pragma unroll
    for (int mi = 0; mi < 2; ++mi)
#pragma unroll
        for (int ni = 0; ni < 8; ++ni)
            acc[mi][ni] = (f32x4){0.f, 0.f, 0.f, 0.f};
    const __hip_bfloat16* wt_base = Wt + (size_t)(bn * 128) * K_DIM;
    const int chunk0 = w * 2;
    const int e0     = chunk0 * 512 + lane * 8;
    const int bn_loc0 = e0 >> 5, bk_off0 = e0 & 31;
    const int e1     = (chunk0 + 1) * 512 + lane * 8;
    const int bn_loc1 = e1 >> 5, bk_off1 = e1 & 31;
    for (int kt = 0; kt < 32; ++kt) {
        const int kb = kt * 32;
        const float* aptr;
        int koff;
        if (kb < IN_DIM) { aptr = x; koff = kb; }
        else             { aptr = h; koff = kb - IN_DIM; }
        async_load16(wt_base + (size_t)bn_loc0 * K_DIM + kb + bk_off0,
                     (void*)(lds_b + chunk0 * 512));
        async_load16(wt_base + (size_t)bn_loc1 * K_DIM + kb + bk_off1,
                     (void*)(lds_b + (chunk0 + 1) * 512));
        float4 av[4];
#pragma unroll
        for (int j = 0; j < 4; ++j) {
            int cch = j * 256 + tid;
            int row = cch >> 3;
            int kq  = (cch & 7) * 4;
            av[j] = *(const float4*)(aptr + (size_t)(bm * 128 + row) * IN_DIM
                                     + koff + kq);
        }
#pragma unroll
        for (int j = 0; j < 4; ++j) {
            int cch = j * 256 + tid;
            int row = cch >> 3;
            int kq  = (cch & 7) * 4;
            short4v sv;
            sv.x = bf16bits(av[j].x);
            sv.y = bf16bits(av[j].y);
            sv.z = bf16bits(av[j].z);
            sv.w = bf16bits(av[j].w);
            *(short4v*)&lds_a[row * 32 + kq] = sv;
        }
        __syncthreads();
        short8 afr[2], bfr[8];
#pragma unroll
        for (int mi = 0; mi < 2; ++mi)
            afr[mi] = *(const short8*)&lds_a[(w * 32 + mi * 16 + col16) * 32 + quad * 8];
#pragma unroll
        for (int ni = 0; ni < 8; ++ni)
            bfr[ni] = *(const short8*)&lds_b[(ni * 16 + col16) * 32 + quad * 8];
#pragma unroll
        for (int mi = 0; mi < 2; ++mi)
#pragma unroll
            for (int ni = 0; ni < 8; ++ni)
                acc[mi][ni] = __builtin_amdgcn_mfma_f32_16x16x32_bf16(
                    afr[mi], bfr[ni], acc[mi][ni], 0, 0, 0);
        __syncthreads();
    }
    float bias_v[4][2];
#pragma unroll
    for (int g = 0; g < 4; ++g)
#pragma unroll
        for (int h2 = 0; h2 < 2; ++h2)
            bias_v[g][h2] = bias_p[bn * 128 + g * 32 + h2 * 16 + col16];
#pragma unroll
    for (int mi = 0; mi < 2; ++mi) {
#pragma unroll
        for (int reg = 0; reg < 4; ++reg) {
            const int m_g = bm * 128 + w * 32 + mi * 16 + quad * 4 + reg;
#pragma unroll
            for (int h2 = 0; h2 < 2; ++h2) {
                const int hc_g = bn * 32 + h2 * 16 + col16;
                float gi = acc[mi][0 + h2][reg] + bias_v[0][h2];
                float gf = acc[mi][2 + h2][reg] + bias_v[1][h2];
                float gg = acc[mi][4 + h2][reg] + bias_v[2][h2];
                float go = acc[mi][6 + h2][reg] + bias_v[3][h2];
                float iv = sigmoidf_(gi);
                float fv = sigmoidf_(gf);
                float gv = tanhf_(gg);
                float ov = sigmoidf_(go);
                float co = c_in[(size_t)m_g * H_DIM + hc_g];
                float cn = fv * co + iv * gv;
                float hn = ov * tanhf_(cn);
                out[(size_t)m_g * H_DIM + hc_g]      = hn;
                out[BH + (size_t)m_g * H_DIM + hc_g] = cn;
            }
        }
    }
}

extern "C" void kernel_launch(void* const* d_in, const int* in_sizes, int n_in,
                              void* d_out, int out_size, void* d_ws, size_t ws_size,
                              hipStream_t stream) {
    const float* x  = (const float*)d_in[0];
    const float* h  = (const float*)d_in[1];
    const float* c  = (const float*)d_in[2];
    const float* Wx = (const float*)d_in[3];
    const float* Wh = (const float*)d_in[4];
    const float* bx = (const float*)d_in[5];
    const float* bh = (const float*)d_in[6];

    const size_t wtBytes  = (size_t)N4H * K_DIM * 2;    // 4 MB
    const size_t axhBytes = (size_t)B_DIM * K_DIM * 2;  // 32 MB
    const size_t need     = wtBytes + axhBytes + (size_t)N4H * 4;

    if (ws_size >= need) {
        __hip_bfloat16* Wt  = (__hip_bfloat16*)d_ws;
        __hip_bfloat16* Axh = (__hip_bfloat16*)((char*)d_ws + wtBytes);
        float* bias_p = (float*)((char*)d_ws + wtBytes + axhBytes);
        prep_all<<<6144, 256, 0, stream>>>(Wx, Wh, bx, bh, x, h, Wt, Axh, bias_p);
        lstm_gemm256<<<512, 512, 0, stream>>>(c, Axh, Wt, bias_p, (float*)d_out);
    } else {
        __hip_bfloat16* Wt = (__hip_bfloat16*)d_ws;
        float* bias_p = (float*)((char*)d_ws + wtBytes);
        prep_weights_fb<<<2048, 256, 0, stream>>>(Wx, Wh, bx, bh, Wt, bias_p);
        lstm_gemm_fb<<<2048, 256, 0, stream>>>(x, h, c, Wt, bias_p, (float*)d_out);
    }
}

// Round 16
// 226.884 us; speedup vs baseline: 3.4359x; 1.0117x over previous
//
#include <hip/hip_runtime.h>
#include <hip/hip_bf16.h>

// Problem constants (fixed by the reference)
#define B_DIM   16384
#define IN_DIM  512
#define H_DIM   512
#define K_DIM   1024          // IN + H concatenated
#define N4H     2048          // 4*H
#define BH      (B_DIM * H_DIM)

typedef __attribute__((ext_vector_type(8))) short  short8;   // 8 bf16 = one MFMA operand / 16B store
typedef __attribute__((ext_vector_type(4))) short  short4v;  // 4 bf16 = 8B write
typedef __attribute__((ext_vector_type(4))) float  f32x4;    // MFMA accumulator

__device__ inline void async_load16(const void* g, void* l) {
    __builtin_amdgcn_global_load_lds(
        (const __attribute__((address_space(1))) void*)g,
        (__attribute__((address_space(3)))       void*)l, 16, 0, 0);
}

__device__ inline short bf16bits(float f) {
    __hip_bfloat16 b = __float2bfloat16(f);
    return *reinterpret_cast<short*>(&b);
}

__device__ inline float sigmoidf_(float v) {
    return 1.0f / (1.0f + __expf(-v));
}
__device__ inline float tanhf_(float v) {
    v = fminf(fmaxf(v, -30.f), 30.f);
    float e = __expf(2.f * v);
    return (e - 1.f) / (e + 1.f);
}

// ---------------------------------------------------------------------------
// Combined prep (r16: Axh half rewritten for 16B writes — G13 sweet spot):
//   blocks [0,2048):      Wt gate-permuted bf16 + packed bias (validated)
//   blocks [2048,10240):  Axh = bf16(x||h), 2 rows/block, thread t:
//     row j=t>>7, chunk c=t&127 -> read 2 x float4 (32B), write 1 short8
//     (16B).  Same bytes to same addresses as prior 8B-write version ->
//     numerics identical; write width 8->16B, Axh-half blocks 4096->8192.
// ---------------------------------------------------------------------------
__global__ __launch_bounds__(256) void prep_all(
    const float* __restrict__ Wx, const float* __restrict__ Wh,
    const float* __restrict__ bx, const float* __restrict__ bh,
    const float* __restrict__ x,  const float* __restrict__ h,
    __hip_bfloat16* __restrict__ Wt, __hip_bfloat16* __restrict__ Axh,
    float* __restrict__ bias_p) {
    const int bid = blockIdx.x;
    const int t   = threadIdx.x;

    if (bid < 2048) {
        __shared__ __hip_bfloat16 tile[32][33];
        const int bk = bid & 31;
        const int bn = bid >> 5;
        const int kb = bk * 32, nb = bn * 32;
#pragma unroll
        for (int r = 0; r < 4; ++r) {
            int k_loc = r * 8 + (t >> 5);
            int n_loc = t & 31;
            int kg = kb + k_loc;
            float v = (kg < IN_DIM) ? Wx[(size_t)kg * N4H + nb + n_loc]
                                    : Wh[(size_t)(kg - IN_DIM) * N4H + nb + n_loc];
            tile[k_loc][n_loc] = __float2bfloat16(v);
        }
        __syncthreads();
        {
            int n_loc = t >> 3;
            int k_loc = (t & 7) * 4;
            int ng = nb + n_loc;
            int g  = ng >> 9;
            int c  = ng & 511;
            int row_out = (c >> 5) * 128 + g * 32 + (c & 31);
            short4v v4;
            v4.x = *reinterpret_cast<short*>(&tile[k_loc + 0][n_loc]);
            v4.y = *reinterpret_cast<short*>(&tile[k_loc + 1][n_loc]);
            v4.z = *reinterpret_cast<short*>(&tile[k_loc + 2][n_loc]);
            v4.w = *reinterpret_cast<short*>(&tile[k_loc + 3][n_loc]);
            *(short4v*)&Wt[(size_t)row_out * K_DIM + kb + k_loc] = v4;
        }
        if (bid < 8) {
            int ng = bid * 256 + t;
            int g  = ng >> 9;
            int c  = ng & 511;
            int ro = (c >> 5) * 128 + g * 32 + (c & 31);
            bias_p[ro] = bx[ng] + bh[ng];
        }
    } else {
        const int ab = bid - 2048;              // 0..8191, 2 rows each
        const int j  = t >> 7;                  // 0..1 (row within pair)
        const int c  = t & 127;                 // chunk of 8 elems in [0,1024)
        const int m  = ab * 2 + j;
        const float* src = (c < 64) ? (x + (size_t)m * 512 + c * 8)
                                    : (h + (size_t)m * 512 + (c - 64) * 8);
        float4 v0 = *(const float4*)(src);
        float4 v1 = *(const float4*)(src + 4);
        short8 sv;
        sv[0] = bf16bits(v0.x); sv[1] = bf16bits(v0.y);
        sv[2] = bf16bits(v0.z); sv[3] = bf16bits(v0.w);
        sv[4] = bf16bits(v1.x); sv[5] = bf16bits(v1.y);
        sv[6] = bf16bits(v1.z); sv[7] = bf16bits(v1.w);
        *(short8*)&Axh[(size_t)m * K_DIM + c * 8] = sv;
    }
}

// ---------------------------------------------------------------------------
// FINAL GEMM (= round 11, best measured & twice-reproduced: 91.5-94.2us,
// MfmaUtil ~31%, FETCH 65.8MB, conflicts 0, VGPR 124).
// ILP-overlapped 256x256 GEMM + fused LSTM epilogue.
// Session ledger: six structurally distinct schedules (2-barrier 128², 4-phase
// counted vmcnt, 2-phase counted, this ILP form, 2-block desync, 4-waves/SIMD
// BK=32) all plateau at 94-110us / MfmaUtil 26-31% with conflicts=0, no
// spill, FETCH minimal — plateau is structural for this N=2048/K=1024 shape
// (~751 TF, consistent with the m97-class reference curve at K=1024).
//   per K-tile: {24 ds_reads} -> {8 gload_lds for tile t+1} -> MFMA ph0 ->
//   MFMA ph1 -> __syncthreads (vmcnt0+lgkm0+barrier = exact tile boundary;
//   DMA has ~2500cy MFMA cover).  No asm waits, no sched pinning.
//   - 512 blocks, XCD mapping (validated, FETCH 66MB)
//   - LDS [dbuf][kh][256r][32k] per array = 128KB; validated additive
//     rotation swizzle, pre-swizzled global source, linear DMA dest;
//     ascending-k accumulation order.
//   - ni == gate -> thread-local LSTM epilogue.
// ---------------------------------------------------------------------------
__global__ __launch_bounds__(512, 2) void lstm_gemm256(
    const float* __restrict__ c_in,
    const __hip_bfloat16* __restrict__ Axh,
    const __hip_bfloat16* __restrict__ Wt,
    const float* __restrict__ bias_p,
    float* __restrict__ out) {
    __shared__ __align__(16) __hip_bfloat16 lds_a[2][16384];  // [dbuf][kh*8192+..]
    __shared__ __align__(16) __hip_bfloat16 lds_b[2][16384];

    const int tid   = threadIdx.x;
    const int w     = tid >> 6;          // wave 0..7
    const int lane  = tid & 63;
    const int col16 = lane & 15;
    const int quad  = lane >> 4;
    const int wm    = w >> 2;            // 0..1  (M half: 128 rows)
    const int wn    = w & 3;             // 0..3  (N quarter: 16ch x 4 gates)

    // validated XCD-aware mapping (FETCH ~66MB): per-XCD 8bm x 8bn
    const int jb    = blockIdx.x;
    const int xcd   = jb & 7;
    const int local = jb >> 3;                   // 0..63
    const int bm    = xcd * 8 + (local >> 3);    // 0..63  (256 A rows each)
    const int bn    = local & 7;                 // 0..7   (256 Wt rows each)

    f32x4 acc[8][4];
#pragma unroll
    for (int mi = 0; mi < 8; ++mi)
#pragma unroll
        for (int ni = 0; ni < 4; ++ni)
            acc[mi][ni] = (f32x4){0.f, 0.f, 0.f, 0.f};

    const __hip_bfloat16* Ab = Axh + (size_t)bm * 256 * K_DIM;
    const __hip_bfloat16* Bb = Wt  + (size_t)bn * 256 * K_DIM;

    // staging: granule = j*512 + tid (16B) -> row j*128 + (tid>>2), phys slot
    // pg = tid&3 holds logical k-octet lq = (pg-(r>>1))&3 (inverse rotation).
    const int lq = ((tid & 3) - ((tid >> 3) & 3)) & 3;

#define STAGE(LDSBUF, GBASE, KH, KT)  do {                                     \
    const __hip_bfloat16* _s = (GBASE) + (size_t)(tid >> 2) * K_DIM            \
                               + (KT) * 64 + (KH) * 32 + lq * 8;               \
    char* _d = (char*)(LDSBUF) + (KH) * 16384 + w * 1024;                      \
    async_load16(_s,                       _d);                                \
    async_load16(_s + (size_t)128 * K_DIM, _d + 8192);                         \
  } while (0)

    // fragment-read byte offsets (validated rotation, 0 conflicts):
    // byte = r*64 + ((quad+((r>>1)&3))&3)*16 within kh-block; kh adds 16384.
    int aoff[8], boff[4];
#pragma unroll
    for (int mi = 0; mi < 8; ++mi) {
        int r = wm * 128 + mi * 16 + col16;
        aoff[mi] = r * 64 + ((quad + ((r >> 1) & 3)) & 3) * 16;
    }
#pragma unroll
    for (int ni = 0; ni < 4; ++ni) {
        int r = (wn >> 1) * 128 + ni * 32 + (wn & 1) * 16 + col16;
        boff[ni] = r * 64 + ((quad + ((r >> 1) & 3)) & 3) * 16;
    }

    // prologue: stage tile 0 into buf 0, publish
    STAGE(lds_a[0], Ab, 0, 0);
    STAGE(lds_b[0], Bb, 0, 0);
    STAGE(lds_a[0], Ab, 1, 0);
    STAGE(lds_b[0], Bb, 1, 0);
    __syncthreads();

    for (int t = 0; t < 16; ++t) {
        const int cur = t & 1;
        const char* la = (const char*)lds_a[cur];
        const char* lb = (const char*)lds_b[cur];
        __hip_bfloat16* nxa = lds_a[cur ^ 1];
        __hip_bfloat16* nxb = lds_b[cur ^ 1];

        // all 24 fragment reads up front: ph0 (kh0) first, ph1 (kh1) second.
        short8 a0[8], b0[4], a1[8], b1[4];
#pragma unroll
        for (int q = 0; q < 8; ++q) a0[q] = *(const short8*)(la + aoff[q]);
#pragma unroll
        for (int n = 0; n < 4; ++n) b0[n] = *(const short8*)(lb + boff[n]);
#pragma unroll
        for (int q = 0; q < 8; ++q) a1[q] = *(const short8*)(la + 16384 + aoff[q]);
#pragma unroll
        for (int n = 0; n < 4; ++n) b1[n] = *(const short8*)(lb + 16384 + boff[n]);

        // stage tile t+1 (8 DMA loads) — drained by this iteration's closing
        // __syncthreads, with the full MFMA region (~2500cy) as cover.
        if (t < 15) {
            STAGE(nxa, Ab, 0, t + 1);
            STAGE(nxb, Bb, 0, t + 1);
            STAGE(nxa, Ab, 1, t + 1);
            STAGE(nxb, Bb, 1, t + 1);
        }

        // MFMA ph0 then ph1 (fine lgkmcnt inserted by the compiler)
        __builtin_amdgcn_s_setprio(1);
#pragma unroll
        for (int q = 0; q < 8; ++q)
#pragma unroll
            for (int n = 0; n < 4; ++n)
                acc[q][n] = __builtin_amdgcn_mfma_f32_16x16x32_bf16(
                    a0[q], b0[n], acc[q][n], 0, 0, 0);
#pragma unroll
        for (int q = 0; q < 8; ++q)
#pragma unroll
            for (int n = 0; n < 4; ++n)
                acc[q][n] = __builtin_amdgcn_mfma_f32_16x16x32_bf16(
                    a1[q], b1[n], acc[q][n], 0, 0, 0);
        __builtin_amdgcn_s_setprio(0);

        // tile boundary: vmcnt(0)+lgkmcnt(0)+barrier (exact semantics needed)
        __syncthreads();
    }
#undef STAGE

    // ---- fused LSTM epilogue (thread-local: ni == gate) ----
    float bias_v[4];
#pragma unroll
    for (int g = 0; g < 4; ++g)
        bias_v[g] = bias_p[bn * 256 + (wn >> 1) * 128 + g * 32 + (wn & 1) * 16 + col16];

    const int hc_g = bn * 64 + (wn >> 1) * 32 + (wn & 1) * 16 + col16;

#pragma unroll
    for (int mi = 0; mi < 8; ++mi) {
#pragma unroll
        for (int reg = 0; reg < 4; ++reg) {
            const int m_g = bm * 256 + wm * 128 + mi * 16 + quad * 4 + reg;
            float gi = acc[mi][0][reg] + bias_v[0];
            float gf = acc[mi][1][reg] + bias_v[1];
            float gg = acc[mi][2][reg] + bias_v[2];
            float go = acc[mi][3][reg] + bias_v[3];
            float iv = sigmoidf_(gi);
            float fv = sigmoidf_(gf);
            float gv = tanhf_(gg);
            float ov = sigmoidf_(go);
            float co = c_in[(size_t)m_g * H_DIM + hc_g];
            float cn = fv * co + iv * gv;
            float hn = ov * tanhf_(cn);
            out[(size_t)m_g * H_DIM + hc_g]      = hn;   // h_new
            out[BH + (size_t)m_g * H_DIM + hc_g] = cn;   // c_new
        }
    }
}

// ---------------------------------------------------------------------------
// Fallback path (validated R1 kernels) in case ws_size < 36 MB.
// ---------------------------------------------------------------------------
__global__ __launch_bounds__(256) void prep_weights_fb(
    const float* __restrict__ Wx, const float* __restrict__ Wh,
    const float* __restrict__ bx, const float* __restrict__ bh,
    __hip_bfloat16* __restrict__ Wt, float* __restrict__ bias_p) {
    __shared__ __hip_bfloat16 tile[32][33];
    const int bid = blockIdx.x;
    const int bk  = bid & 31;
    const int bn  = bid >> 5;
    const int t   = threadIdx.x;
    const int kb  = bk * 32, nb = bn * 32;
#pragma unroll
    for (int r = 0; r < 4; ++r) {
        int k_loc = r * 8 + (t >> 5);
        int n_loc = t & 31;
        int kg = kb + k_loc;
        float v = (kg < IN_DIM) ? Wx[(size_t)kg * N4H + nb + n_loc]
                                : Wh[(size_t)(kg - IN_DIM) * N4H + nb + n_loc];
        tile[k_loc][n_loc] = __float2bfloat16(v);
    }
    __syncthreads();
    {
        int n_loc = t >> 3;
        int k_loc = (t & 7) * 4;
        int ng = nb + n_loc;
        int g  = ng >> 9;
        int c  = ng & 511;
        int row_out = (c >> 5) * 128 + g * 32 + (c & 31);
        short4v v4;
        v4.x = *reinterpret_cast<short*>(&tile[k_loc + 0][n_loc]);
        v4.y = *reinterpret_cast<short*>(&tile[k_loc + 1][n_loc]);
        v4.z = *reinterpret_cast<short*>(&tile[k_loc + 2][n_loc]);
        v4.w = *reinterpret_cast<short*>(&tile[k_loc + 3][n_loc]);
        *(short4v*)&Wt[(size_t)row_out * K_DIM + kb + k_loc] = v4;
    }
    if (bid < 8) {
        int ng = bid * 256 + t;
        int g  = ng >> 9;
        int c  = ng & 511;
        int ro = (c >> 5) * 128 + g * 32 + (c & 31);
        bias_p[ro] = bx[ng] + bh[ng];
    }
}

__global__ __launch_bounds__(256, 3) void lstm_gemm_fb(
    const float* __restrict__ x, const float* __restrict__ h,
    const float* __restrict__ c_in,
    const __hip_bfloat16* __restrict__ Wt, const float* __restrict__ bias_p,
    float* __restrict__ out) {
    __shared__ __hip_bfloat16 lds_a[128 * 32];
    __shared__ __hip_bfloat16 lds_b[128 * 32];
    const int tid   = threadIdx.x;
    const int bn    = blockIdx.x & 15;
    const int bm    = blockIdx.x >> 4;
    const int w     = tid >> 6;
    const int lane  = tid & 63;
    const int col16 = lane & 15;
    const int quad  = lane >> 4;
    f32x4 acc[2][8];
#pragma unroll
    for (int mi = 0; mi < 2; ++mi)
#pragma unroll
        for (int ni = 0; ni < 8; ++ni)
            acc[mi][ni] = (f32x4){0.f, 0.f, 0.f, 0.f};
    const __hip_bfloat16* wt_base = Wt + (size_t)(bn * 128) * K_DIM;
    const int chunk0 = w * 2;
    const int e0     = chunk0 * 512 + lane * 8;
    const int bn_loc0 = e0 >> 5, bk_off0 = e0 & 31;
    const int e1     = (chunk0 + 1) * 512 + lane * 8;
    const int bn_loc1 = e1 >> 5, bk_off1 = e1 & 31;
    for (int kt = 0; kt < 32; ++kt) {
        const int kb = kt * 32;
        const float* aptr;
        int koff;
        if (kb < IN_DIM) { aptr = x; koff = kb; }
        else             { aptr = h; koff = kb - IN_DIM; }
        async_load16(wt_base + (size_t)bn_loc0 * K_DIM + kb + bk_off0,
                     (void*)(lds_b + chunk0 * 512));
        async_load16(wt_base + (size_t)bn_loc1 * K_DIM + kb + bk_off1,
                     (void*)(lds_b + (chunk0 + 1) * 512));
        float4 av[4];
#pragma unroll
        for (int j = 0; j < 4; ++j) {
            int cch = j * 256 + tid;
            int row = cch >> 3;
            int kq  = (cch & 7) * 4;
            av[j] = *(const float4*)(aptr + (size_t)(bm * 128 + row) * IN_DIM
                                     + koff + kq);
        }
#pragma unroll
        for (int j = 0; j < 4; ++j) {
            int cch = j * 256 + tid;
            int row = cch >> 3;
            int kq  = (cch & 7) * 4;
            short4v sv;
            sv.x = bf16bits(av[j].x);
            sv.y = bf16bits(av[j].y);
            sv.z = bf16bits(av[j].z);
            sv.w = bf16bits(av[j].w);
            *(short4v*)&lds_a[row * 32 + kq] = sv;
        }
        __syncthreads();
        short8 afr[2], bfr[8];
#pragma unroll
        for (int mi = 0; mi < 2; ++mi)
            afr[mi] = *(const short8*)&lds_a[(w * 32 + mi * 16 + col16) * 32 + quad * 8];
#pragma unroll
        for (int ni = 0; ni < 8; ++ni)
            bfr[ni] = *(const short8*)&lds_b[(ni * 16 + col16) * 32 + quad * 8];
#pragma unroll
        for (int mi = 0; mi < 2; ++mi)
#pragma unroll
            for (int ni = 0; ni < 8; ++ni)
                acc[mi][ni] = __builtin_amdgcn_mfma_f32_16x16x32_bf16(
                    afr[mi], bfr[ni], acc[mi][ni], 0, 0, 0);
        __syncthreads();
    }
    float bias_v[4][2];
#pragma unroll
    for (int g = 0; g < 4; ++g)
#pragma unroll
        for (int h2 = 0; h2 < 2; ++h2)
            bias_v[g][h2] = bias_p[bn * 128 + g * 32 + h2 * 16 + col16];
#pragma unroll
    for (int mi = 0; mi < 2; ++mi) {
#pragma unroll
        for (int reg = 0; reg < 4; ++reg) {
            const int m_g = bm * 128 + w * 32 + mi * 16 + quad * 4 + reg;
#pragma unroll
            for (int h2 = 0; h2 < 2; ++h2) {
                const int hc_g = bn * 32 + h2 * 16 + col16;
                float gi = acc[mi][0 + h2][reg] + bias_v[0][h2];
                float gf = acc[mi][2 + h2][reg] + bias_v[1][h2];
                float gg = acc[mi][4 + h2][reg] + bias_v[2][h2];
                float go = acc[mi][6 + h2][reg] + bias_v[3][h2];
                float iv = sigmoidf_(gi);
                float fv = sigmoidf_(gf);
                float gv = tanhf_(gg);
                float ov = sigmoidf_(go);
                float co = c_in[(size_t)m_g * H_DIM + hc_g];
                float cn = fv * co + iv * gv;
                float hn = ov * tanhf_(cn);
                out[(size_t)m_g * H_DIM + hc_g]      = hn;
                out[BH + (size_t)m_g * H_DIM + hc_g] = cn;
            }
        }
    }
}

extern "C" void kernel_launch(void* const* d_in, const int* in_sizes, int n_in,
                              void* d_out, int out_size, void* d_ws, size_t ws_size,
                              hipStream_t stream) {
    const float* x  = (const float*)d_in[0];
    const float* h  = (const float*)d_in[1];
    const float* c  = (const float*)d_in[2];
    const float* Wx = (const float*)d_in[3];
    const float* Wh = (const float*)d_in[4];
    const float* bx = (const float*)d_in[5];
    const float* bh = (const float*)d_in[6];

    const size_t wtBytes  = (size_t)N4H * K_DIM * 2;    // 4 MB
    const size_t axhBytes = (size_t)B_DIM * K_DIM * 2;  // 32 MB
    const size_t need     = wtBytes + axhBytes + (size_t)N4H * 4;

    if (ws_size >= need) {
        __hip_bfloat16* Wt  = (__hip_bfloat16*)d_ws;
        __hip_bfloat16* Axh = (__hip_bfloat16*)((char*)d_ws + wtBytes);
        float* bias_p = (float*)((char*)d_ws + wtBytes + axhBytes);
        prep_all<<<10240, 256, 0, stream>>>(Wx, Wh, bx, bh, x, h, Wt, Axh, bias_p);
        lstm_gemm256<<<512, 512, 0, stream>>>(c, Axh, Wt, bias_p, (float*)d_out);
    } else {
        __hip_bfloat16* Wt = (__hip_bfloat16*)d_ws;
        float* bias_p = (float*)((char*)d_ws + wtBytes);
        prep_weights_fb<<<2048, 256, 0, stream>>>(Wx, Wh, bx, bh, Wt, bias_p);
        lstm_gemm_fb<<<2048, 256, 0, stream>>>(x, h, c, Wt, bias_p, (float*)d_out);
    }
}